// Round 1
// baseline (697.586 us; speedup 1.0000x reference)
//
#include <hip/hip_runtime.h>

typedef short short8 __attribute__((ext_vector_type(8)));
typedef float floatx4 __attribute__((ext_vector_type(4)));

// ---------- helpers ----------
__device__ __forceinline__ unsigned short f2bf(float f) {
  union { float f; unsigned int i; } v; v.f = f;
  return (unsigned short)((v.i + 0x7fffu + ((v.i >> 16) & 1u)) >> 16);
}
__device__ __forceinline__ float ftanh(float x) {
  float e = __expf(2.f * x);
  return 1.f - 2.f / (e + 1.f);
}

// ---------- weight permutation into MFMA B-fragment order ----------
// Fragment: 64 lanes x 8 bf16; lane: n = lane&15, k = (lane>>4)*8 + e.
// W0f: frag id = (loc*2 + nt)*2 + ks   (400 locs, N=32 -> 2 nt, K=64 -> 2 ks)
//      k-order kk = NATURAL W0 order c*9 + r*3 + l  (kk>=54 -> 0)
// W1f: frag id = (loc*4 + nt)*4 + ks   (100 locs, N=64 -> 4 nt, K=128 -> 4 ks)
//      k-order: kk = kl*32 + c   (kl = si*2+sj over L0 sub-locs, c = L0 cout)
// W2f: frag id = (loc*8 + nt)*50 + ks  (4 locs, N=128 -> 8 nt, K=1600 -> 50 ks)
//      k-order: kk = kl5*64 + c  (kl5 = di*5+dj over L1 sub-locs, c = L1 cout)
__global__ __launch_bounds__(256) void k_permute(const float* __restrict__ W0,
                                                 const float* __restrict__ W1,
                                                 const float* __restrict__ W2,
                                                 unsigned short* __restrict__ W0f,
                                                 unsigned short* __restrict__ W1f,
                                                 unsigned short* __restrict__ W2f) {
  int idx = blockIdx.x * 256 + threadIdx.x;      // 3 * 819200
  int sec = idx / 819200;
  int q = idx - sec * 819200;
  int frag = q >> 9, li = q & 511;
  int lane = li >> 3, e = li & 7;
  int n = lane & 15, quad = lane >> 4;
  if (sec == 0) {
    int loc = frag >> 2, nt = (frag >> 1) & 1, ks = frag & 1;
    int kk = (ks << 5) + (quad << 3) + e;
    int co = (nt << 4) + n;
    unsigned short v = 0;
    if (kk < 54) v = f2bf(W0[loc * 1728 + co * 54 + kk]);
    W0f[q] = v;
  } else if (sec == 1) {
    int loc = frag >> 4, nt = (frag >> 2) & 3, ks = frag & 3;
    int kk = (ks << 5) + (quad << 3) + e;
    int kl = kk >> 5, c = kk & 31, co = (nt << 4) + n;
    W1f[q] = f2bf(W1[(size_t)loc * 8192 + (co << 7) + (c << 2) + kl]);
  } else {
    int g = frag / 50, ks = frag - g * 50;
    int loc = g >> 3, nt = g & 7;
    int kk = (ks << 5) + (quad << 3) + e;
    int kl5 = kk >> 6, c = kk & 63, co = (nt << 4) + n;
    W2f[q] = f2bf(W2[(size_t)loc * 204800 + co * 1600 + c * 25 + kl5]);
  }
}

// ---------- fused L0+L1+L2: block = 16 samples x 1 output quadrant ----------
// 25 iterations over L1 locs: {stage 6x6x6 x-patch -> sX | L0 (wave=subloc) -> sA |
//  L1 (wave=nt), overlapped with next stage} then phase-2 L2 GEMM from sH.
// grid (4 quadrants FASTEST, 256 b-tiles) so blocks sharing x boundary lines co-run.
// LDS: sX 8448 + sA 4352 + sH 51456 = 64256 B -> 2 blocks/CU.
__global__ __launch_bounds__(256, 2) void k_fused(const float* __restrict__ x,
                                                  const short8* __restrict__ W0f,
                                                  const float* __restrict__ B0,
                                                  const short8* __restrict__ W1f,
                                                  const float* __restrict__ B1,
                                                  const short8* __restrict__ W2f,
                                                  const float* __restrict__ B2,
                                                  float* __restrict__ h2) {
  const int t = threadIdx.x, lane = t & 63, w = t >> 6;
  const int n16 = lane & 15, quad = lane >> 4;
  const int q = blockIdx.x;                 // quadrant = L2 loc = I*2+J
  const int b0 = blockIdx.y << 4;
  const int i0 = (q >> 1) * 5, j0 = (q & 1) * 5;

  // sX: [16 b][4 subloc][64 k] bf16, b-pitch 264 (132 dw == 4 mod 32 -> 2-way banks)
  // sA: [16 b][128 k] bf16, b-pitch 136 (68 dw == 4 mod 32 -> 2-way banks)
  // sH: [16 m][1600 k] bf16, pitch 1608 (same as previous k_l12)
  __shared__ __align__(16) unsigned short sX[16 * 264];
  __shared__ __align__(16) unsigned short sA[16 * 136];
  __shared__ __align__(16) unsigned short sH[16 * 1608];

  const floatx4 z = {0.f, 0.f, 0.f, 0.f};
  const float* xq = x + (size_t)b0 * 21600;

  // zero k-pad 54..63 for every (b, subloc) -- written once, never overwritten
  if (t < 64) {
    unsigned int* d = (unsigned int*)&sX[(t >> 2) * 264 + (t & 3) * 64 + 54];
    d[0] = 0u; d[1] = 0u; d[2] = 0u; d[3] = 0u; d[4] = 0u;
  }

  // stage the 6x6 patch (per channel) at L1 loc (gi,gj): 576 units of (b,c,rr),
  // 6 floats each (3x float2, 8B-aligned), split into sublocs (si*2) / (si*2+1).
  auto stage = [&](int gi, int gj) {
    const float* base = xq + gi * 360 + gj * 6;
#pragma unroll
    for (int uu = 0; uu < 3; ++uu) {
      int u = t + (uu << 8);
      if (uu == 2 && t >= 64) continue;     // 576 = 2*256 + 64
      int b = u / 36, rem = u - b * 36;
      int c = rem / 6, rr = rem - c * 6;
      const float2* p = (const float2*)(base + (size_t)b * 21600 + c * 3600 + rr * 60);
      float2 v0 = p[0], v1 = p[1], v2 = p[2];
      int si = (rr >= 3) ? 1 : 0, r = rr - si * 3;
      unsigned short* d0 = &sX[b * 264 + (si << 1) * 64 + c * 9 + r * 3];
      d0[0]  = f2bf(v0.x); d0[1]  = f2bf(v0.y); d0[2]  = f2bf(v1.x);
      d0[64] = f2bf(v1.y); d0[65] = f2bf(v2.x); d0[66] = f2bf(v2.y);
    }
  };

  stage(i0, j0);
  __syncthreads();

  for (int li = 0; li < 25; ++li) {
    const int di = li / 5, dj = li - di * 5;
    const int gi = i0 + di, gj = j0 + dj;

    // ---- L0: wave w owns subloc s = w (L0 loc (2gi+si, 2gj+sj))
    {
      const int s = w;
      const int loc0 = (2 * gi + (s >> 1)) * 20 + (2 * gj + (s & 1));
      short8 a0 = *(const short8*)&sX[n16 * 264 + s * 64 + (quad << 3)];
      short8 a1 = *(const short8*)&sX[n16 * 264 + s * 64 + 32 + (quad << 3)];
      short8 b00 = W0f[((loc0 << 2) + 0) * 64 + lane];
      short8 b01 = W0f[((loc0 << 2) + 1) * 64 + lane];
      short8 b10 = W0f[((loc0 << 2) + 2) * 64 + lane];
      short8 b11 = W0f[((loc0 << 2) + 3) * 64 + lane];
      floatx4 acc0 = z, acc1 = z;
      acc0 = __builtin_amdgcn_mfma_f32_16x16x32_bf16(a0, b00, acc0, 0, 0, 0);
      acc0 = __builtin_amdgcn_mfma_f32_16x16x32_bf16(a1, b01, acc0, 0, 0, 0);
      acc1 = __builtin_amdgcn_mfma_f32_16x16x32_bf16(a0, b10, acc1, 0, 0, 0);
      acc1 = __builtin_amdgcn_mfma_f32_16x16x32_bf16(a1, b11, acc1, 0, 0, 0);
      float bias0 = B0[loc0 * 32 + n16];
      float bias1 = B0[loc0 * 32 + 16 + n16];
#pragma unroll
      for (int reg = 0; reg < 4; ++reg) {
        unsigned short* dd = &sA[((quad << 2) + reg) * 136 + (s << 5) + n16];
        dd[0]  = f2bf(ftanh(acc0[reg] + bias0));
        dd[16] = f2bf(ftanh(acc1[reg] + bias1));
      }
    }
    __syncthreads();   // sA ready for L1; sX free for next stage

    if (li < 24) {
      const int lin = li + 1;
      const int din = lin / 5, djn = lin - din * 5;
      stage(i0 + din, j0 + djn);           // overlaps with L1 below
    }

    // ---- L1: wave w owns nt = w
    {
      const int loc1 = gi * 10 + gj;
      short8 a0 = *(const short8*)&sA[n16 * 136 + 0  + (quad << 3)];
      short8 a1 = *(const short8*)&sA[n16 * 136 + 32 + (quad << 3)];
      short8 a2 = *(const short8*)&sA[n16 * 136 + 64 + (quad << 3)];
      short8 a3 = *(const short8*)&sA[n16 * 136 + 96 + (quad << 3)];
      const short8* wb = W1f + (size_t)(((loc1 << 2) + w) << 2) * 64 + lane;
      floatx4 acc = z;
      acc = __builtin_amdgcn_mfma_f32_16x16x32_bf16(a0, wb[0],   acc, 0, 0, 0);
      acc = __builtin_amdgcn_mfma_f32_16x16x32_bf16(a1, wb[64],  acc, 0, 0, 0);
      acc = __builtin_amdgcn_mfma_f32_16x16x32_bf16(a2, wb[128], acc, 0, 0, 0);
      acc = __builtin_amdgcn_mfma_f32_16x16x32_bf16(a3, wb[192], acc, 0, 0, 0);
      float bias = B1[(loc1 << 6) + (w << 4) + n16];
      int col = (li << 6) + (w << 4) + n16;
#pragma unroll
      for (int reg = 0; reg < 4; ++reg)
        sH[((quad << 2) + reg) * 1608 + col] = f2bf(ftanh(acc[reg] + bias));
    }
    __syncthreads();   // sX staged + sA consumed before next L0
  }

  // ---- phase 2: L2 GEMM [16x1600]*[1600x128] from sH; wave w owns nt = 2w, 2w+1
  floatx4 acc0 = z, acc1 = z;
  const short8* wb0 = W2f + (size_t)(((q << 3) + (w << 1)) * 50) * 64 + lane;
  const short8* wb1 = wb0 + (size_t)50 * 64;
  for (int ks = 0; ks < 50; ++ks) {
    short8 a = *(const short8*)&sH[n16 * 1608 + (ks << 5) + (quad << 3)];
    acc0 = __builtin_amdgcn_mfma_f32_16x16x32_bf16(a, wb0[ks * 64], acc0, 0, 0, 0);
    acc1 = __builtin_amdgcn_mfma_f32_16x16x32_bf16(a, wb1[ks * 64], acc1, 0, 0, 0);
  }

#pragma unroll
  for (int u = 0; u < 2; ++u) {
    const floatx4& ac = u ? acc1 : acc0;
    int co = (((w << 1) + u) << 4) + n16;
    float bias = B2[(q << 7) + co];
#pragma unroll
    for (int reg = 0; reg < 4; ++reg) {
      int bb = b0 + (quad << 2) + reg;
      h2[(size_t)bb * 512 + (co << 2) + q] = ftanh(ac[reg] + bias);
    }
  }
}

// ---------- classifier + softmax: one wave per sample ----------
__global__ __launch_bounds__(256) void k_cls(const float* __restrict__ h2,
                                             const float* __restrict__ info,
                                             const float* __restrict__ Wc,
                                             const float* __restrict__ bc,
                                             float* __restrict__ out) {
  const int l = threadIdx.x & 63;
  const int b = blockIdx.x * 4 + (threadIdx.x >> 6);
  const float* hrow = h2 + (size_t)b * 512;
  float p0 = 0.f, p1 = 0.f;
#pragma unroll
  for (int f = 0; f < 512; f += 64) {
    float h = hrow[f + l];
    p0 = fmaf(h, Wc[2 * (f + l)], p0);
    p1 = fmaf(h, Wc[2 * (f + l) + 1], p1);
  }
#pragma unroll
  for (int m = 32; m; m >>= 1) {
    p0 += __shfl_xor(p0, m, 64);
    p1 += __shfl_xor(p1, m, 64);
  }
  if (l == 0) {
    float i0 = info[2 * b], i1 = info[2 * b + 1];
    float l0 = p0 + i0 * Wc[1024] + i1 * Wc[1026] + bc[0];
    float l1 = p1 + i0 * Wc[1025] + i1 * Wc[1027] + bc[1];
    float mx = fmaxf(l0, l1);
    float e0 = __expf(l0 - mx), e1 = __expf(l1 - mx);
    float inv = 1.f / (e0 + e1);
    out[2 * b]     = e0 * inv;
    out[2 * b + 1] = e1 * inv;
  }
}

extern "C" void kernel_launch(void* const* d_in, const int* in_sizes, int n_in,
                              void* d_out, int out_size, void* d_ws, size_t ws_size,
                              hipStream_t stream) {
  const float* x    = (const float*)d_in[0];
  const float* info = (const float*)d_in[1];
  const float* W0   = (const float*)d_in[2];
  const float* B0   = (const float*)d_in[3];
  const float* W1   = (const float*)d_in[4];
  const float* B1   = (const float*)d_in[5];
  const float* W2   = (const float*)d_in[6];
  const float* B2   = (const float*)d_in[7];
  const float* Wc   = (const float*)d_in[8];
  const float* bc   = (const float*)d_in[9];
  float* out = (float*)d_out;

  // ws layout (13.3 MB; h0 eliminated by fusion):
  //   [0, 8388608)            h2 fp32 [4096][512]
  //   [8388608,  +1638400)    W0f bf16 frags
  //   [10027008, +1638400)    W1f bf16 frags
  //   [11665408, +1638400)    W2f bf16 frags
  char* ws = (char*)d_ws;
  float*          h2  = (float*)ws;
  unsigned short* W0f = (unsigned short*)(ws + 8388608);
  unsigned short* W1f = (unsigned short*)(ws + 10027008);
  unsigned short* W2f = (unsigned short*)(ws + 11665408);

  k_permute<<<dim3(9600),    dim3(256), 0, stream>>>(W0, W1, W2, W0f, W1f, W2f);
  k_fused  <<<dim3(4, 256),  dim3(256), 0, stream>>>(x, (const short8*)W0f, B0,
                                                     (const short8*)W1f, B1,
                                                     (const short8*)W2f, B2, h2);
  k_cls    <<<dim3(1024),    dim3(256), 0, stream>>>(h2, info, Wc, bc, out);
}

// Round 2
// 596.619 us; speedup vs baseline: 1.1692x; 1.1692x over previous
//
#include <hip/hip_runtime.h>

typedef short short8 __attribute__((ext_vector_type(8)));
typedef float floatx4 __attribute__((ext_vector_type(4)));

// ---------- helpers ----------
__device__ __forceinline__ unsigned short f2bf(float f) {
  union { float f; unsigned int i; } v; v.f = f;
  return (unsigned short)((v.i + 0x7fffu + ((v.i >> 16) & 1u)) >> 16);
}
__device__ __forceinline__ float ftanh(float x) {
  float e = __expf(2.f * x);
  return 1.f - 2.f / (e + 1.f);
}

// ---------- weight permutation into MFMA B-fragment order (unchanged) ----------
// Fragment: 64 lanes x 8 bf16; lane: n = lane&15, k = (lane>>4)*8 + e.
// W0f: frag id = (loc*2 + nt)*2 + ks   (400 locs, N=32 -> 2 nt, K=64 -> 2 ks)
//      k-order kk = NATURAL W0 order c*9 + r*3 + l  (kk>=54 -> 0)
// W1f: frag id = (loc*4 + nt)*4 + ks   (100 locs, N=64 -> 4 nt, K=128 -> 4 ks)
//      k-order: kk = kl*32 + c   (kl = si*2+sj over L0 sub-locs, c = L0 cout)
// W2f: frag id = (loc*8 + nt)*50 + ks  (4 locs, N=128 -> 8 nt, K=1600 -> 50 ks)
//      k-order: kk = kl5*64 + c  (kl5 = di*5+dj over L1 sub-locs, c = L1 cout)
__global__ __launch_bounds__(256) void k_permute(const float* __restrict__ W0,
                                                 const float* __restrict__ W1,
                                                 const float* __restrict__ W2,
                                                 unsigned short* __restrict__ W0f,
                                                 unsigned short* __restrict__ W1f,
                                                 unsigned short* __restrict__ W2f) {
  int idx = blockIdx.x * 256 + threadIdx.x;      // 3 * 819200
  int sec = idx / 819200;
  int q = idx - sec * 819200;
  int frag = q >> 9, li = q & 511;
  int lane = li >> 3, e = li & 7;
  int n = lane & 15, quad = lane >> 4;
  if (sec == 0) {
    int loc = frag >> 2, nt = (frag >> 1) & 1, ks = frag & 1;
    int kk = (ks << 5) + (quad << 3) + e;
    int co = (nt << 4) + n;
    unsigned short v = 0;
    if (kk < 54) v = f2bf(W0[loc * 1728 + co * 54 + kk]);
    W0f[q] = v;
  } else if (sec == 1) {
    int loc = frag >> 4, nt = (frag >> 2) & 3, ks = frag & 3;
    int kk = (ks << 5) + (quad << 3) + e;
    int kl = kk >> 5, c = kk & 31, co = (nt << 4) + n;
    W1f[q] = f2bf(W1[(size_t)loc * 8192 + (co << 7) + (c << 2) + kl]);
  } else {
    int g = frag / 50, ks = frag - g * 50;
    int loc = g >> 3, nt = g & 7;
    int kk = (ks << 5) + (quad << 3) + e;
    int kl5 = kk >> 6, c = kk & 63, co = (nt << 4) + n;
    W2f[q] = f2bf(W2[(size_t)loc * 204800 + co * 1600 + c * 25 + kl5]);
  }
}

// ---------- fused L0+L1: block = 16 samples x 1 L1-row (gi) x half-width (jh) ----------
// Two si passes: stage 3 x-rows (30 cols, 6 ch, 16 b) into sX (contiguous 120-B
// half-row reads via float2), L0 (20 units = 10 jj x 2 nt) -> sA in W1 k-order.
// Then L1 (wave w = nt1, 5 gjl locs) -> h1 global in [q][kl5][b][c64] layout.
// LDS: sX 20736 + sA 20736 = 41472 B -> 3 blocks/CU. 5 barriers total.
// pitch 648 ush = 324 dw == 4 mod 32 -> ds_read_b128 across n16 is 2-way (free).
__global__ __launch_bounds__(256, 3) void k_l01(const float* __restrict__ x,
                                                const short8* __restrict__ W0f,
                                                const float* __restrict__ B0,
                                                const short8* __restrict__ W1f,
                                                const float* __restrict__ B1,
                                                unsigned short* __restrict__ h1) {
  const int t = threadIdx.x, lane = t & 63, w = t >> 6;
  const int n16 = lane & 15, quad = lane >> 4;
  const int gi = blockIdx.x >> 1, jh = blockIdx.x & 1;   // gi 0..9, jh 0..1
  const int b0 = blockIdx.y << 4;

  __shared__ __align__(16) unsigned short sX[16 * 648];  // [b][jj(10)][k(64)]
  __shared__ __align__(16) unsigned short sA[16 * 648];  // [b][gjl(5)][kl(4)][c(32)]

  // zero k-pad 54..63 for every (b, jj) -- stage never touches k>=54
  if (t < 160) {
    unsigned int* d = (unsigned int*)&sX[(t / 10) * 648 + (t % 10) * 64 + 54];
    d[0] = 0u; d[1] = 0u; d[2] = 0u; d[3] = 0u; d[4] = 0u;
  }

  const floatx4 z = {0.f, 0.f, 0.f, 0.f};

#pragma unroll
  for (int si = 0; si < 2; ++si) {
    __syncthreads();                       // sX free (pad done / prev L0 done)
    // ---- stage: 288 units of (b, c, r); each reads 30 contiguous floats
    for (int u = t; u < 288; u += 256) {
      int b = u / 18, rem = u - b * 18;
      int c = rem / 3, r = rem - c * 3;
      const float* px = x + ((size_t)(b0 + b) * 6 + c) * 3600
                          + (6 * gi + 3 * si + r) * 60 + 30 * jh;
      unsigned short* dst = &sX[b * 648 + c * 9 + r * 3];
#pragma unroll
      for (int m = 0; m < 15; ++m) {
        float2 v = *(const float2*)(px + 2 * m);
        const int c0 = 2 * m, c1 = 2 * m + 1;
        dst[(c0 / 3) * 64 + (c0 % 3)] = f2bf(v.x);
        dst[(c1 / 3) * 64 + (c1 % 3)] = f2bf(v.y);
      }
    }
    __syncthreads();
    // ---- L0: 20 units (jj, nt); wave w takes u = w, w+4, ..., w+16
#pragma unroll
    for (int m = 0; m < 5; ++m) {
      const int u = w + (m << 2);
      const int jj = u >> 1, nt = u & 1;
      const int loc0 = (2 * gi + si) * 20 + 10 * jh + jj;
      short8 a0 = *(const short8*)&sX[n16 * 648 + jj * 64 + (quad << 3)];
      short8 a1 = *(const short8*)&sX[n16 * 648 + jj * 64 + 32 + (quad << 3)];
      short8 bf0 = W0f[(loc0 * 4 + nt * 2 + 0) * 64 + lane];
      short8 bf1 = W0f[(loc0 * 4 + nt * 2 + 1) * 64 + lane];
      floatx4 acc = z;
      acc = __builtin_amdgcn_mfma_f32_16x16x32_bf16(a0, bf0, acc, 0, 0, 0);
      acc = __builtin_amdgcn_mfma_f32_16x16x32_bf16(a1, bf1, acc, 0, 0, 0);
      const float bias = B0[loc0 * 32 + nt * 16 + n16];
      const int base = (jj >> 1) * 128 + (si * 2 + (jj & 1)) * 32 + nt * 16 + n16;
#pragma unroll
      for (int reg = 0; reg < 4; ++reg)
        sA[((quad << 2) + reg) * 648 + base] = f2bf(ftanh(acc[reg] + bias));
    }
  }
  __syncthreads();

  // ---- L1: wave w = nt1; 5 gjl locs each
  const int q2 = (gi >= 5 ? 2 : 0) + jh;
  const int di = gi - (gi >= 5 ? 5 : 0);
#pragma unroll
  for (int gjl = 0; gjl < 5; ++gjl) {
    const int loc1 = gi * 10 + 5 * jh + gjl;
    short8 a0 = *(const short8*)&sA[n16 * 648 + gjl * 128 + 0  + (quad << 3)];
    short8 a1 = *(const short8*)&sA[n16 * 648 + gjl * 128 + 32 + (quad << 3)];
    short8 a2 = *(const short8*)&sA[n16 * 648 + gjl * 128 + 64 + (quad << 3)];
    short8 a3 = *(const short8*)&sA[n16 * 648 + gjl * 128 + 96 + (quad << 3)];
    const short8* wb = W1f + (size_t)((loc1 * 4 + w) * 4) * 64 + lane;
    floatx4 acc = z;
    acc = __builtin_amdgcn_mfma_f32_16x16x32_bf16(a0, wb[0],   acc, 0, 0, 0);
    acc = __builtin_amdgcn_mfma_f32_16x16x32_bf16(a1, wb[64],  acc, 0, 0, 0);
    acc = __builtin_amdgcn_mfma_f32_16x16x32_bf16(a2, wb[128], acc, 0, 0, 0);
    acc = __builtin_amdgcn_mfma_f32_16x16x32_bf16(a3, wb[192], acc, 0, 0, 0);
    const float bias = B1[loc1 * 64 + w * 16 + n16];
    const int kl5 = di * 5 + gjl;
    unsigned short* ob = h1 + ((size_t)(q2 * 25 + kl5) * 4096) * 64 + w * 16 + n16;
#pragma unroll
    for (int reg = 0; reg < 4; ++reg) {
      int bb = b0 + (quad << 2) + reg;
      ob[(size_t)bb * 64] = f2bf(ftanh(acc[reg] + bias));
    }
  }
}

// ---------- L2: [16 x 1600] * [1600 x 128] per (b-tile, quadrant), no LDS ----------
// h1 layout [q][kl5(25)][b(4096)][c(64)] -> A-frag loads are 16x64-B dense lines.
// Software-pipelined 1 kl5 deep; wave w owns nt = 2w, 2w+1.
__global__ __launch_bounds__(256) void k_l2(const unsigned short* __restrict__ h1,
                                            const short8* __restrict__ W2f,
                                            const float* __restrict__ B2,
                                            float* __restrict__ h2) {
  const int t = threadIdx.x, lane = t & 63, w = t >> 6;
  const int n16 = lane & 15, quad = lane >> 4;
  const int q = blockIdx.x;
  const int b0 = blockIdx.y << 4;
  const floatx4 z = {0.f, 0.f, 0.f, 0.f};

  const unsigned short* Ab = h1 + ((size_t)q * 25 * 4096 + b0 + n16) * 64 + (quad << 3);
  const short8* wb0 = W2f + (size_t)(((q << 3) + (w << 1)) * 50) * 64 + lane;
  const short8* wb1 = wb0 + (size_t)50 * 64;

  floatx4 acc0 = z, acc1 = z;
  short8 aA = *(const short8*)&Ab[0];
  short8 aB = *(const short8*)&Ab[32];
  for (int kl5 = 0; kl5 < 25; ++kl5) {
    short8 nA = aA, nB = aB;
    if (kl5 < 24) {
      const unsigned short* p = Ab + (size_t)(kl5 + 1) * 262144;
      nA = *(const short8*)&p[0];
      nB = *(const short8*)&p[32];
    }
    const int ks = kl5 * 2;
    acc0 = __builtin_amdgcn_mfma_f32_16x16x32_bf16(aA, wb0[ks * 64], acc0, 0, 0, 0);
    acc1 = __builtin_amdgcn_mfma_f32_16x16x32_bf16(aA, wb1[ks * 64], acc1, 0, 0, 0);
    acc0 = __builtin_amdgcn_mfma_f32_16x16x32_bf16(aB, wb0[(ks + 1) * 64], acc0, 0, 0, 0);
    acc1 = __builtin_amdgcn_mfma_f32_16x16x32_bf16(aB, wb1[(ks + 1) * 64], acc1, 0, 0, 0);
    aA = nA; aB = nB;
  }

#pragma unroll
  for (int u = 0; u < 2; ++u) {
    const floatx4& ac = u ? acc1 : acc0;
    int co = (((w << 1) + u) << 4) + n16;
    float bias = B2[(q << 7) + co];
#pragma unroll
    for (int reg = 0; reg < 4; ++reg) {
      int bb = b0 + (quad << 2) + reg;
      h2[(size_t)bb * 512 + (co << 2) + q] = ftanh(ac[reg] + bias);
    }
  }
}

// ---------- classifier + softmax: one wave per sample ----------
__global__ __launch_bounds__(256) void k_cls(const float* __restrict__ h2,
                                             const float* __restrict__ info,
                                             const float* __restrict__ Wc,
                                             const float* __restrict__ bc,
                                             float* __restrict__ out) {
  const int l = threadIdx.x & 63;
  const int b = blockIdx.x * 4 + (threadIdx.x >> 6);
  const float* hrow = h2 + (size_t)b * 512;
  float p0 = 0.f, p1 = 0.f;
#pragma unroll
  for (int f = 0; f < 512; f += 64) {
    float h = hrow[f + l];
    p0 = fmaf(h, Wc[2 * (f + l)], p0);
    p1 = fmaf(h, Wc[2 * (f + l) + 1], p1);
  }
#pragma unroll
  for (int m = 32; m; m >>= 1) {
    p0 += __shfl_xor(p0, m, 64);
    p1 += __shfl_xor(p1, m, 64);
  }
  if (l == 0) {
    float i0 = info[2 * b], i1 = info[2 * b + 1];
    float l0 = p0 + i0 * Wc[1024] + i1 * Wc[1026] + bc[0];
    float l1 = p1 + i0 * Wc[1025] + i1 * Wc[1027] + bc[1];
    float mx = fmaxf(l0, l1);
    float e0 = __expf(l0 - mx), e1 = __expf(l1 - mx);
    float inv = 1.f / (e0 + e1);
    out[2 * b]     = e0 * inv;
    out[2 * b + 1] = e1 * inv;
  }
}

extern "C" void kernel_launch(void* const* d_in, const int* in_sizes, int n_in,
                              void* d_out, int out_size, void* d_ws, size_t ws_size,
                              hipStream_t stream) {
  const float* x    = (const float*)d_in[0];
  const float* info = (const float*)d_in[1];
  const float* W0   = (const float*)d_in[2];
  const float* B0   = (const float*)d_in[3];
  const float* W1   = (const float*)d_in[4];
  const float* B1   = (const float*)d_in[5];
  const float* W2   = (const float*)d_in[6];
  const float* B2   = (const float*)d_in[7];
  const float* Wc   = (const float*)d_in[8];
  const float* bc   = (const float*)d_in[9];
  float* out = (float*)d_out;

  // ws layout (65.7 MB):
  //   [0, 52428800)            h1 bf16 [4 q][25 kl5][4096 b][64 c]
  //   [52428800, +8388608)     h2 fp32 [4096][512]
  //   [60817408, +1638400)     W0f bf16 frags
  //   [62455808, +1638400)     W1f bf16 frags
  //   [64094208, +1638400)     W2f bf16 frags
  char* ws = (char*)d_ws;
  unsigned short* h1  = (unsigned short*)ws;
  float*          h2  = (float*)(ws + 52428800);
  unsigned short* W0f = (unsigned short*)(ws + 60817408);
  unsigned short* W1f = (unsigned short*)(ws + 62455808);
  unsigned short* W2f = (unsigned short*)(ws + 64094208);

  k_permute<<<dim3(9600),    dim3(256), 0, stream>>>(W0, W1, W2, W0f, W1f, W2f);
  k_l01    <<<dim3(20, 256), dim3(256), 0, stream>>>(x, (const short8*)W0f, B0,
                                                     (const short8*)W1f, B1, h1);
  k_l2     <<<dim3(4, 256),  dim3(256), 0, stream>>>(h1, (const short8*)W2f, B2, h2);
  k_cls    <<<dim3(1024),    dim3(256), 0, stream>>>(h2, info, Wc, bc, out);
}